// Round 2
// baseline (185.772 us; speedup 1.0000x reference)
//
#include <hip/hip_runtime.h>
#include <math.h>

#define T_N 100000
#define H_N 256
#define NT ((T_N + 63) / 64)          // 1563 row-tiles for k_at
#define CT_TILE 128
#define NCT ((T_N + CT_TILE - 1) / CT_TILE)  // 782 tiles for k_ct

typedef __attribute__((ext_vector_type(8))) __bf16 bf16x8;
typedef __attribute__((ext_vector_type(4))) __bf16 bf16x4;
typedef __attribute__((ext_vector_type(4))) float f32x4;

// ws layout (bytes):
//       0 : WmT bf16 [256][256]   (131072)
//  131072 : proj f32 [256]        (1024)
//  132096 : At   f32 [100000]     (400000)
//  532096 : partials float2[256]  (2048)
//  534144 : lse  f32              (4)

__device__ __forceinline__ float tanh_fast(float x) {
    // tanh(x) = 1 - 2/(exp(2x)+1); saturates correctly for large |x| (exp->inf or 0)
    float e = __expf(2.0f * x);
    return 1.0f - 2.0f / (e + 1.0f);
}

// ---------------------------------------------------------------- prep
__global__ __launch_bounds__(256) void k_prep(const float* __restrict__ Wm,
                                              const float* __restrict__ hc,
                                              const float* __restrict__ W1,
                                              __bf16* __restrict__ WmT,
                                              float* __restrict__ proj,
                                              float* __restrict__ out) {
    const int j = blockIdx.x;   // 0..255 output row of WmT / proj index
    const int t = threadIdx.x;  // 0..255
    // WmT[j][k] = Wm[k][j], converted to bf16 (B^T row-major, k-contiguous)
    WmT[j * H_N + t] = (__bf16)Wm[t * H_N + j];
    // proj[j] = sum_k hc[k] * W1[j][k]
    __shared__ float red[H_N];
    red[t] = hc[t] * W1[j * H_N + t];
    __syncthreads();
    for (int off = 128; off > 0; off >>= 1) {
        if (t < off) red[t] += red[t + off];
        __syncthreads();
    }
    if (t == 0) proj[j] = red[0];
    // zero the ct accumulator region of d_out (atomics land here in k_ct)
    if (j == 0) out[T_N + t] = 0.0f;
}

// ---------------------------------------------------------------- At = tanh(Mt@Wm + proj) @ V
// 4 waves/block; wave w owns output cols [64w, 64w+64). B held in registers
// (loaded once per block from L2-resident WmT); grid-stride over 64-row tiles.
__global__ __launch_bounds__(256, 2) void k_at(const float* __restrict__ Mt,
                                               const __bf16* __restrict__ WmT,
                                               const float* __restrict__ proj,
                                               const float* __restrict__ V,
                                               float* __restrict__ At) {
    const int tid = threadIdx.x;
    const int lane = tid & 63;
    const int w = tid >> 6;     // wave 0..3
    const int l15 = lane & 15;
    const int lg = lane >> 4;   // 0..3

    __shared__ __align__(16) char sA[64 * 256 * 2];  // 32 KB, [row][k] bf16, XOR-swizzled
    __shared__ float part[4][64];

    // ---- B fragments resident in registers: breg[ks][fc]
    // col n = 64w + 16fc + l15 ; k = 32ks + lg*8 .. +8
    bf16x8 breg[8][4];
#pragma unroll
    for (int ks = 0; ks < 8; ++ks) {
        const int k = 32 * ks + lg * 8;
#pragma unroll
        for (int fc = 0; fc < 4; ++fc) {
            const int n = 64 * w + 16 * fc + l15;
            breg[ks][fc] = *(const bf16x8*)(WmT + n * H_N + k);
        }
    }
    float pj[4], vj[4];
#pragma unroll
    for (int fc = 0; fc < 4; ++fc) {
        const int n = 64 * w + 16 * fc + l15;
        pj[fc] = proj[n];
        vj[fc] = V[n];
    }

    for (int tile = blockIdx.x; tile < NT; tile += gridDim.x) {
        const int t0 = tile * 64;
        // ---- stage A tile: 64 rows x 256 k, fp32 -> bf16, swizzled
#pragma unroll
        for (int it = 0; it < 16; ++it) {
            int q = tid + 256 * it;       // float4 index
            int row = q >> 6;             // 64 float4 per row
            int kp = (q & 63) << 2;
            int t = t0 + row;
            float4 v = make_float4(0.f, 0.f, 0.f, 0.f);
            if (t < T_N) v = *(const float4*)(Mt + (size_t)t * H_N + kp);
            bf16x4 b4;
            b4[0] = (__bf16)v.x; b4[1] = (__bf16)v.y; b4[2] = (__bf16)v.z; b4[3] = (__bf16)v.w;
            int off = (row * 512 + kp * 2) ^ ((row & 7) << 4);
            *(bf16x4*)(sA + off) = b4;
        }
        __syncthreads();

        f32x4 acc[4][4];
#pragma unroll
        for (int m = 0; m < 4; ++m)
#pragma unroll
            for (int fc = 0; fc < 4; ++fc) {
                f32x4 z = {0.f, 0.f, 0.f, 0.f};
                acc[m][fc] = z;
            }

#pragma unroll
        for (int ks = 0; ks < 8; ++ks) {
            const int kA = 32 * ks + lg * 8;
            bf16x8 afrag[4];
#pragma unroll
            for (int m = 0; m < 4; ++m) {
                int r = 16 * m + l15;
                int off = (r * 512 + kA * 2) ^ ((r & 7) << 4);
                afrag[m] = *(const bf16x8*)(sA + off);
            }
#pragma unroll
            for (int m = 0; m < 4; ++m)
#pragma unroll
                for (int fc = 0; fc < 4; ++fc)
                    acc[m][fc] = __builtin_amdgcn_mfma_f32_16x16x32_bf16(
                        afrag[m], breg[ks][fc], acc[m][fc], 0, 0, 0);
        }

        // ---- epilogue: row partial = sum_{cols of wave} tanh(y + proj)*V
#pragma unroll
        for (int m = 0; m < 4; ++m) {
#pragma unroll
            for (int i = 0; i < 4; ++i) {
                float p = 0.0f;
#pragma unroll
                for (int fc = 0; fc < 4; ++fc)
                    p += tanh_fast(acc[m][fc][i] + pj[fc]) * vj[fc];
                p += __shfl_xor(p, 1);
                p += __shfl_xor(p, 2);
                p += __shfl_xor(p, 4);
                p += __shfl_xor(p, 8);
                if (l15 == 0) part[w][16 * m + lg * 4 + i] = p;
            }
        }
        __syncthreads();
        if (tid < 64) {
            int t = t0 + tid;
            if (t < T_N)
                At[t] = part[0][tid] + part[1][tid] + part[2][tid] + part[3][tid];
        }
        // next tile's stage-A writes to sA only happen after every wave passed
        // the barrier above (all sA reads done); part[] readers are protected
        // because the next part[] write sits behind the next post-stage barrier.
    }
}

// ---------------------------------------------------------------- LSE stage 1: 256 blocks of partial (m, s)
__global__ __launch_bounds__(256) void k_lse_part(const float* __restrict__ At,
                                                  float2* __restrict__ part) {
    const int tid = threadIdx.x;
    const int gid = blockIdx.x * 256 + tid;
    float m = -INFINITY, s = 0.0f;
    for (int i = gid; i < T_N; i += 256 * 256) {
        float x = At[i];
        if (x > m) { s = s * __expf(m - x) + 1.0f; m = x; }
        else s += __expf(x - m);
    }
    __shared__ float ms[256], ss[256];
    ms[tid] = m; ss[tid] = s;
    __syncthreads();
    for (int off = 128; off > 0; off >>= 1) {
        if (tid < off) {
            float m2 = ms[tid + off], s2 = ss[tid + off];
            float M = fmaxf(ms[tid], m2);
            ss[tid] = ss[tid] * __expf(ms[tid] - M) + s2 * __expf(m2 - M);
            ms[tid] = M;
        }
        __syncthreads();
    }
    if (tid == 0) part[blockIdx.x] = make_float2(ms[0], ss[0]);
}

// ---------------------------------------------------------------- LSE stage 2: combine 256 partials
__global__ __launch_bounds__(256) void k_lse_final(const float2* __restrict__ part,
                                                   float* __restrict__ lse) {
    const int tid = threadIdx.x;
    __shared__ float ms[256], ss[256];
    float2 p = part[tid];
    ms[tid] = p.x; ss[tid] = p.y;
    __syncthreads();
    for (int off = 128; off > 0; off >>= 1) {
        if (tid < off) {
            float m2 = ms[tid + off], s2 = ss[tid + off];
            float M = fmaxf(ms[tid], m2);
            ss[tid] = ss[tid] * __expf(ms[tid] - M) + s2 * __expf(m2 - M);
            ms[tid] = M;
        }
        __syncthreads();
    }
    if (tid == 0) *lse = ms[0] + logf(ss[0]);
}

// ---------------------------------------------------------------- alphat write + ct = alphat @ Mt
// 128-row tiles; thread (tid&63) owns float4 cols [4c,4c+4), (tid>>6) picks a
// 32-row group. Register accumulation across tiles, one LDS reduce + 4 atomics.
__global__ __launch_bounds__(256) void k_ct(const float* __restrict__ Mt,
                                            const float* __restrict__ At,
                                            const float* __restrict__ lse,
                                            float* __restrict__ out) {
    const float L = *lse;
    const int tid = threadIdx.x;
    const int c4 = (tid & 63) << 2;  // float4 col base
    const int rg = tid >> 6;         // row group 0..3 -> rows [32rg, 32rg+32)
    __shared__ float al[CT_TILE];
    __shared__ float4 red[256];
    float4 acc = make_float4(0.f, 0.f, 0.f, 0.f);

    for (int tile = blockIdx.x; tile < NCT; tile += gridDim.x) {
        const int t0 = tile * CT_TILE;
        __syncthreads();  // protect al[] from previous-iter readers
        if (tid < CT_TILE) {
            int t = t0 + tid;
            float a = 0.0f;
            if (t < T_N) { a = At[t] - L; out[t] = a; }
            al[tid] = a;
        }
        __syncthreads();
        const int r0 = rg * 32;
#pragma unroll 4
        for (int r = 0; r < 32; ++r) {
            int t = t0 + r0 + r;
            if (t >= T_N) break;
            float a = al[r0 + r];
            const float4 mv = *(const float4*)(Mt + (size_t)t * H_N + c4);
            acc.x += a * mv.x; acc.y += a * mv.y;
            acc.z += a * mv.z; acc.w += a * mv.w;
        }
    }
    red[tid] = acc;
    __syncthreads();
    if (tid < 64) {
        float4 s = red[tid];
        const float4 b = red[tid + 64], c = red[tid + 128], d = red[tid + 192];
        s.x += b.x + c.x + d.x; s.y += b.y + c.y + d.y;
        s.z += b.z + c.z + d.z; s.w += b.w + c.w + d.w;
        atomicAdd(&out[T_N + c4 + 0], s.x);
        atomicAdd(&out[T_N + c4 + 1], s.y);
        atomicAdd(&out[T_N + c4 + 2], s.z);
        atomicAdd(&out[T_N + c4 + 3], s.w);
    }
}

// ----------------------------------------------------------------
extern "C" void kernel_launch(void* const* d_in, const int* in_sizes, int n_in,
                              void* d_out, int out_size, void* d_ws, size_t ws_size,
                              hipStream_t stream) {
    const float* inputs = (const float*)d_in[0];  // (T, H)
    const float* hc     = (const float*)d_in[1];  // (1, H)
    const float* Wm     = (const float*)d_in[2];  // (H, H)
    const float* V      = (const float*)d_in[3];  // (H, 1)
    const float* W1     = (const float*)d_in[4];  // (H, H)
    float* out = (float*)d_out;                   // [alphat (T) | ct (H)]

    char* ws = (char*)d_ws;
    __bf16* WmT = (__bf16*)ws;
    float* proj = (float*)(ws + 131072);
    float* At   = (float*)(ws + 132096);
    float2* part = (float2*)(ws + 532096);
    float* lse  = (float*)(ws + 534144);

    k_prep<<<256, 256, 0, stream>>>(Wm, hc, W1, WmT, proj, out);
    k_at<<<512, 256, 0, stream>>>(inputs, WmT, proj, V, At);
    k_lse_part<<<256, 256, 0, stream>>>(At, part);
    k_lse_final<<<1, 256, 0, stream>>>(part, lse);
    k_ct<<<782, 256, 0, stream>>>(inputs, At, lse, out);
}

// Round 3
// 83.276 us; speedup vs baseline: 2.2308x; 2.2308x over previous
//
#include <hip/hip_runtime.h>
#include <math.h>

#define T_N 100000
#define H_N 256
#define TM 32                  // tile rows
#define NT (T_N / TM)          // 3125 exact, no tail
#define GRID_AT 512

typedef __attribute__((ext_vector_type(8))) __bf16 bf16x8;
typedef __attribute__((ext_vector_type(4))) __bf16 bf16x4;
typedef __attribute__((ext_vector_type(4))) float f32x4;

// ws layout (bytes):
//       0 : WmT bf16 [256][256]   (131072)
//  131072 : proj f32 [256]        (1024)
//  132096 : At   f32 [100000]     (400000)
//  532096 : part2 float2[512]     (4096)
//  536192 : s1g  f32[256]         (1024)
//  537216 : s0g  f32[256]         (1024)
//  538240 : lse  f32              (4)

__device__ __forceinline__ float tanh_fast(float x) {
    // tanh(x) = 1 - 2/(exp(2x)+1); saturates correctly for large |x|
    float e = __expf(2.0f * x);
    return 1.0f - 2.0f / (e + 1.0f);
}

// ---------------------------------------------------------------- prep
__global__ __launch_bounds__(256) void k_prep(const float* __restrict__ Wm,
                                              const float* __restrict__ hc,
                                              const float* __restrict__ W1,
                                              __bf16* __restrict__ WmT,
                                              float* __restrict__ proj,
                                              float* __restrict__ s1g,
                                              float* __restrict__ s0g) {
    const int j = blockIdx.x;   // 0..255
    const int t = threadIdx.x;  // 0..255
    WmT[j * H_N + t] = (__bf16)Wm[t * H_N + j];   // B^T, k-contiguous
    __shared__ float red[H_N];
    red[t] = hc[t] * W1[j * H_N + t];
    __syncthreads();
    for (int off = 128; off > 0; off >>= 1) {
        if (t < off) red[t] += red[t + off];
        __syncthreads();
    }
    if (t == 0) proj[j] = red[0];
    if (j == 0) { s1g[t] = 0.0f; s0g[t] = 0.0f; }  // zero ct accumulators
}

// ---------------------------------------------------------------- fused At + LSE partials + ct partials
// 4 waves/block; wave w owns cols [64w,64w+64) (breg in regs). 32-row tiles,
// double-buffered LDS, 4-slab staging pipelined one full tile ahead.
__global__ __launch_bounds__(256, 2) void k_at(const float* __restrict__ Mt,
                                               const __bf16* __restrict__ WmT,
                                               const float* __restrict__ proj,
                                               const float* __restrict__ V,
                                               float* __restrict__ At,
                                               float2* __restrict__ part2,
                                               float* __restrict__ s1g,
                                               float* __restrict__ s0g) {
    const int tid = threadIdx.x;
    const int lane = tid & 63;
    const int w = tid >> 6;
    const int l15 = lane & 15;
    const int lg = lane >> 4;
    const int rg = tid >> 5;   // 0..7  (ct row group)
    const int cg = tid & 31;   // 0..31 (ct col group: cols 8cg..8cg+8)

    __shared__ __align__(16) char sA[2][TM * 512];  // 2 x 16 KB bf16, XOR-swizzled
    __shared__ float part[4][TM];

    // ---- B resident in registers: col n = 64w+16fc+l15, k = 32ks+8lg
    bf16x8 breg[8][4];
#pragma unroll
    for (int ks = 0; ks < 8; ++ks) {
        const int k = 32 * ks + 8 * lg;
#pragma unroll
        for (int fc = 0; fc < 4; ++fc)
            breg[ks][fc] = *(const bf16x8*)(WmT + (64 * w + 16 * fc + l15) * H_N + k);
    }
    float pj[4], vj[4];
#pragma unroll
    for (int fc = 0; fc < 4; ++fc) {
        const int n = 64 * w + 16 * fc + l15;
        pj[fc] = proj[n];
        vj[fc] = V[n];
    }

    // staging map: slab = 32 rows x 64 k fp32 = 512 float4; idx=it*256+tid
    auto stage_load = [&](int tile, int s, float4 (&S)[2]) {
#pragma unroll
        for (int it = 0; it < 2; ++it) {
            const int idx = it * 256 + tid;
            const int row = idx >> 4, kq = idx & 15;
            if (tile < NT)
                S[it] = *(const float4*)(Mt + (size_t)(tile * TM + row) * H_N + 64 * s + kq * 4);
            else
                S[it] = make_float4(0.f, 0.f, 0.f, 0.f);
        }
    };
    auto stage_write = [&](int buf, int s, const float4 (&S)[2]) {
#pragma unroll
        for (int it = 0; it < 2; ++it) {
            const int idx = it * 256 + tid;
            const int row = idx >> 4, kq = idx & 15;
            bf16x4 b;
            b[0] = (__bf16)S[it].x; b[1] = (__bf16)S[it].y;
            b[2] = (__bf16)S[it].z; b[3] = (__bf16)S[it].w;
            const int off = (row * 512 + 128 * s + kq * 8) ^ ((row & 7) << 4);
            *(bf16x4*)(&sA[buf][off]) = b;
        }
    };

    float s1a[8] = {0.f, 0.f, 0.f, 0.f, 0.f, 0.f, 0.f, 0.f};
    float s0a[8] = {0.f, 0.f, 0.f, 0.f, 0.f, 0.f, 0.f, 0.f};
    float lm = -INFINITY, ls = 0.0f;

    int tile = blockIdx.x;
    float4 S[4][2];  // 4 rotating staging sets (slab p of next tile)
    {
        float4 Sp[2];
#pragma unroll
        for (int s = 0; s < 4; ++s) { stage_load(tile, s, Sp); stage_write(0, s, Sp); }
    }
#pragma unroll
    for (int s = 0; s < 4; ++s) stage_load(tile + GRID_AT, s, S[s]);
    __syncthreads();

    int cur = 0;
    for (; tile < NT; tile += GRID_AT) {
        const int nt1 = tile + GRID_AT;
        f32x4 acc[2][4];
#pragma unroll
        for (int m = 0; m < 2; ++m)
#pragma unroll
            for (int fc = 0; fc < 4; ++fc) {
                f32x4 z = {0.f, 0.f, 0.f, 0.f};
                acc[m][fc] = z;
            }

#pragma unroll
        for (int ph = 0; ph < 4; ++ph) {
            // compute slab ph of cur: ks = 2ph, 2ph+1
#pragma unroll
            for (int kk = 0; kk < 2; ++kk) {
                const int ks = 2 * ph + kk;
                bf16x8 af[2];
#pragma unroll
                for (int m = 0; m < 2; ++m) {
                    const int r = 16 * m + l15;
                    const int off = (r * 512 + 64 * ks + 16 * lg) ^ ((r & 7) << 4);
                    af[m] = *(const bf16x8*)(&sA[cur][off]);
                }
#pragma unroll
                for (int m = 0; m < 2; ++m)
#pragma unroll
                    for (int fc = 0; fc < 4; ++fc)
                        acc[m][fc] = __builtin_amdgcn_mfma_f32_16x16x32_bf16(
                            af[m], breg[ks][fc], acc[m][fc], 0, 0, 0);
            }
            // consume staged slab ph of tile nt1 (issued a full tile ago), reissue
            if (nt1 < NT) {
                stage_write(cur ^ 1, ph, S[ph]);
                stage_load(nt1 + GRID_AT, ph, S[ph]);  // auto-zero if >= NT
            }
        }

        // ---- epilogue: row partials over this wave's 64 cols
#pragma unroll
        for (int m = 0; m < 2; ++m)
#pragma unroll
            for (int i = 0; i < 4; ++i) {
                float p = 0.f;
#pragma unroll
                for (int fc = 0; fc < 4; ++fc)
                    p += tanh_fast(acc[m][fc][i] + pj[fc]) * vj[fc];
                p += __shfl_xor(p, 1);
                p += __shfl_xor(p, 2);
                p += __shfl_xor(p, 4);
                p += __shfl_xor(p, 8);
                if (l15 == 0) part[w][16 * m + 4 * lg + i] = p;
            }
        __syncthreads();  // A: part[] visible; nxt fully written; cur reads done

        if (tid < TM) {
            const float at = part[0][tid] + part[1][tid] + part[2][tid] + part[3][tid];
            At[tile * TM + tid] = at;
            if (at > lm) { ls = ls * __expf(lm - at) + 1.0f; lm = at; }
            else ls += __expf(at - lm);
        }
        // ct partials from the bf16 tile still in LDS: rows r=8j+rg, cols 8cg..+8
#pragma unroll
        for (int j = 0; j < 4; ++j) {
            const int r = 8 * j + rg;
            const float at_r = part[0][r] + part[1][r] + part[2][r] + part[3][r];
            const int off = (r * 512 + cg * 16) ^ ((r & 7) << 4);
            const bf16x8 vrow = *(const bf16x8*)(&sA[cur][off]);
#pragma unroll
            for (int q = 0; q < 8; ++q) {
                const float x = (float)vrow[q];
                s1a[q] += at_r * x;
                s0a[q] += x;
            }
        }
        __syncthreads();  // B: cur reads done before next tile overwrites it
        cur ^= 1;
    }

    // ---- block-level reduce of ct partials (reuse sA), then global atomics
    float* red1 = (float*)&sA[0][0];  // [8][256]
    float* red2 = (float*)&sA[1][0];
#pragma unroll
    for (int q = 0; q < 8; ++q) {
        red1[rg * 256 + cg * 8 + q] = s1a[q];
        red2[rg * 256 + cg * 8 + q] = s0a[q];
    }
    __syncthreads();
    {
        float a1 = 0.f, a0 = 0.f;
#pragma unroll
        for (int g = 0; g < 8; ++g) {
            a1 += red1[g * 256 + tid];
            a0 += red2[g * 256 + tid];
        }
        atomicAdd(&s1g[tid], a1);
        atomicAdd(&s0g[tid], a0);
    }
    // ---- block LSE partial: tid<32 hold (lm,ls); reduce within wave 0
    if (w == 0) {
#pragma unroll
        for (int d = 1; d < 32; d <<= 1) {
            const float m2 = __shfl_xor(lm, d), s2 = __shfl_xor(ls, d);
            const float M = fmaxf(lm, m2);
            ls = ls * __expf(lm - M) + s2 * __expf(m2 - M);
            lm = M;
        }
        if (lane == 0) part2[blockIdx.x] = make_float2(lm, ls);
    }
}

// ---------------------------------------------------------------- final: LSE + ct
__global__ __launch_bounds__(512) void k_final(const float2* __restrict__ part2,
                                               const float* __restrict__ s1g,
                                               const float* __restrict__ s0g,
                                               float* __restrict__ lse,
                                               float* __restrict__ out) {
    const int tid = threadIdx.x;
    __shared__ float ms[512], ss[512];
    const float2 p = part2[tid];
    ms[tid] = p.x; ss[tid] = p.y;
    __syncthreads();
    for (int off = 256; off > 0; off >>= 1) {
        if (tid < off) {
            const float m2 = ms[tid + off], s2 = ss[tid + off];
            const float M = fmaxf(ms[tid], m2);
            ss[tid] = ss[tid] * __expf(ms[tid] - M) + s2 * __expf(m2 - M);
            ms[tid] = M;
        }
        __syncthreads();
    }
    __shared__ float Ls;
    if (tid == 0) { Ls = ms[0] + logf(ss[0]); *lse = Ls; }
    __syncthreads();
    if (tid < H_N) out[T_N + tid] = s1g[tid] - Ls * s0g[tid];
}

// ---------------------------------------------------------------- alphat = At - LSE
__global__ __launch_bounds__(256) void k_alpha(const float* __restrict__ At,
                                               const float* __restrict__ lse,
                                               float* __restrict__ out) {
    const float L = *lse;
    const int i4 = blockIdx.x * 256 + threadIdx.x;
    if (i4 < T_N / 4) {
        float4 a = *(const float4*)(At + i4 * 4);
        a.x -= L; a.y -= L; a.z -= L; a.w -= L;
        *(float4*)(out + i4 * 4) = a;
    }
}

// ----------------------------------------------------------------
extern "C" void kernel_launch(void* const* d_in, const int* in_sizes, int n_in,
                              void* d_out, int out_size, void* d_ws, size_t ws_size,
                              hipStream_t stream) {
    const float* inputs = (const float*)d_in[0];  // (T, H)
    const float* hc     = (const float*)d_in[1];  // (1, H)
    const float* Wm     = (const float*)d_in[2];  // (H, H)
    const float* V      = (const float*)d_in[3];  // (H, 1)
    const float* W1     = (const float*)d_in[4];  // (H, H)
    float* out = (float*)d_out;                   // [alphat (T) | ct (H)]

    char* ws = (char*)d_ws;
    __bf16* WmT  = (__bf16*)ws;
    float* proj  = (float*)(ws + 131072);
    float* At    = (float*)(ws + 132096);
    float2* p2   = (float2*)(ws + 532096);
    float* s1g   = (float*)(ws + 536192);
    float* s0g   = (float*)(ws + 537216);
    float* lse   = (float*)(ws + 538240);

    k_prep<<<256, 256, 0, stream>>>(Wm, hc, W1, WmT, proj, s1g, s0g);
    k_at<<<GRID_AT, 256, 0, stream>>>(inputs, WmT, proj, V, At, p2, s1g, s0g);
    k_final<<<1, 512, 0, stream>>>(p2, s1g, s0g, lse, out);
    k_alpha<<<98, 256, 0, stream>>>(At, lse, out);
}